// Round 1
// baseline (156.926 us; speedup 1.0000x reference)
//
#include <hip/hip_runtime.h>
#include <hip/hip_bf16.h>

// Submanifold sparse conv, N=100k pts, 128^3 grid, Cin=Cout=32, 27 offsets.
// Strategy: dense voxel->index grid (130^3 int32 = 8.8 MB in d_ws), built with
// atomicMin (reference resolves duplicate voxels to the MIN original index via
// stable argsort + searchsorted-left). Conv kernel: 8 points/block, thread =
// (point, cout); skip absent neighbors (only ~2.2/27 present on average).

#define GRID_B 130                      // key base (G + 2)
#define GRID_CELLS (GRID_B * GRID_B * GRID_B)
#define C_IN 32
#define C_OUT 32
#define PTS_PER_BLOCK 8
#define EMPTY_SENTINEL 0x7F7F7F7F       // memset byte 0x7F; > any valid index

__global__ void build_grid_kernel(const int* __restrict__ pos,
                                  int* __restrict__ grid, int n) {
    int i = blockIdx.x * blockDim.x + threadIdx.x;
    if (i >= n) return;
    int x = pos[3 * i + 0] + 1;
    int y = pos[3 * i + 1] + 1;
    int z = pos[3 * i + 2] + 1;
    int key = (x * GRID_B + y) * GRID_B + z;
    atomicMin(&grid[key], i);
}

__global__ void conv_kernel(const float* __restrict__ feat,
                            const int* __restrict__ pos,
                            const float* __restrict__ weight,
                            const int* __restrict__ grid,
                            float* __restrict__ out, int n) {
    __shared__ int nbr[PTS_PER_BLOCK][27];
    const int block_base = blockIdx.x * PTS_PER_BLOCK;
    const int tid = threadIdx.x;

    // Phase 1: 8 pts x 27 offsets = 216 neighbor lookups.
    if (tid < PTS_PER_BLOCK * 27) {
        int p = tid / 27;
        int o = tid % 27;
        int pt = block_base + p;
        int j = EMPTY_SENTINEL;
        if (pt < n) {
            // offset order matches meshgrid(ij).reshape(27,3):
            // dx = o/9 - 1, dy = (o/3)%3 - 1, dz = o%3 - 1
            int x = pos[3 * pt + 0] + (o / 9) - 1 + 1;
            int y = pos[3 * pt + 1] + ((o / 3) % 3) - 1 + 1;
            int z = pos[3 * pt + 2] + (o % 3) - 1 + 1;
            int key = (x * GRID_B + y) * GRID_B + z;
            j = grid[key];
        }
        nbr[p][o] = j;
    }
    __syncthreads();

    // Phase 2: thread = (point p, output channel cout)
    const int p = tid >> 5;
    const int cout = tid & 31;
    const int pt = block_base + p;
    if (pt >= n) return;

    float acc = 0.0f;
    for (int o = 0; o < 27; ++o) {
        int j = nbr[p][o];
        if (j < n) {                    // neighbor present (~2.2 of 27)
            const float* __restrict__ f = feat + j * C_IN;
            const float* __restrict__ wp = weight + o * C_IN * C_OUT + cout;
            #pragma unroll
            for (int c = 0; c < C_IN; ++c) {
                acc = fmaf(f[c], wp[c * C_OUT], acc);   // f[c]: 32-lane broadcast; wp: coalesced
            }
        }
    }
    out[pt * C_OUT + cout] = acc;
}

extern "C" void kernel_launch(void* const* d_in, const int* in_sizes, int n_in,
                              void* d_out, int out_size, void* d_ws, size_t ws_size,
                              hipStream_t stream) {
    const float* features = (const float*)d_in[0];
    const int*   positions = (const int*)d_in[1];
    const float* weight = (const float*)d_in[2];
    float* out = (float*)d_out;
    const int n = in_sizes[0] / C_IN;   // 100000

    int* grid = (int*)d_ws;             // GRID_CELLS ints = 8.788 MB

    // Init grid to EMPTY_SENTINEL (every byte 0x7F). Capturable memset node.
    hipMemsetAsync(grid, 0x7F, (size_t)GRID_CELLS * sizeof(int), stream);

    {
        dim3 block(256);
        dim3 gridDim((n + 255) / 256);
        build_grid_kernel<<<gridDim, block, 0, stream>>>(positions, grid, n);
    }
    {
        dim3 block(PTS_PER_BLOCK * 32);  // 256
        dim3 gridDim((n + PTS_PER_BLOCK - 1) / PTS_PER_BLOCK);
        conv_kernel<<<gridDim, block, 0, stream>>>(features, positions, weight,
                                                   grid, out, n);
    }
}